// Round 1
// baseline (297.136 us; speedup 1.0000x reference)
//
#include <hip/hip_runtime.h>
#include <math.h>

#define B_ 4
#define N_ 256
#define D_ 128
#define H_ 256
#define K_ 8
#define JT 64

// Kernel 0: avec[bi][k] = b1[k] + sum_d s_i[d]*W1[d][k]
//           bvec[bi][k] =         sum_d s_i[d]*W1[D+d][k]
__global__ __launch_bounds__(256) void precompute_ab(
    const float* __restrict__ s, const float* __restrict__ W1,
    const float* __restrict__ b1,
    float* __restrict__ avec, float* __restrict__ bvec)
{
    int bi = blockIdx.x;
    int t = threadIdx.x;
    __shared__ float si[D_];
    if (t < D_) si[t] = s[(size_t)bi * D_ + t];
    __syncthreads();
    float a = b1[t], bb = 0.f;
    #pragma unroll 8
    for (int d = 0; d < D_; ++d) {
        float sv = si[d];
        a  = fmaf(sv, W1[(size_t)d * H_ + t], a);
        bb = fmaf(sv, W1[(size_t)(D_ + d) * H_ + t], bb);
    }
    avec[(size_t)bi * H_ + t] = a;
    bvec[(size_t)bi * H_ + t] = bb;
}

// Kernel A: scores[b,i,j] = b2 + sum_k relu(a_i[k] + b_j[k] + sum_d s_i[d]s_j[d]W1c[d][k]) * W2[k]
// One block per (b,i). 4 waves; wave g owns k-slice [64g, 64g+64); lane owns j within a 64-wide j-tile.
__global__ __launch_bounds__(256) void scores_kernel(
    const float* __restrict__ s, const float* __restrict__ W1,
    const float* __restrict__ W2, const float* __restrict__ b2,
    const float* __restrict__ avec, const float* __restrict__ bvec,
    float* __restrict__ scores)
{
    int bi = blockIdx.x;
    int b = bi >> 8;            // N_==256
    int t = threadIdx.x;
    int lane = t & 63;
    int wid = t >> 6;

    __shared__ float sish[D_];
    __shared__ float P[JT * (D_ + 1)];     // +1 pad: bank=(jj+d)%32 -> 2-way (free)
    __shared__ float partial[4][JT];

    const float* si = s + (size_t)bi * D_;
    const float* Sb = s + (size_t)b * N_ * D_;

    if (t < D_) sish[t] = si[t];
    __syncthreads();

    // Force wave-uniformity so W1c / avec / W2 loads can scalarize to s_load.
    int g = __builtin_amdgcn_readfirstlane(wid);
    const float* Wc  = W1 + (size_t)2 * D_ * H_ + g * 64;  // W1c[d][g*64+kk] = Wc[d*H_ + kk]
    const float* aiP = avec + (size_t)bi * H_ + g * 64;
    const float* w2P = W2 + g * 64;
    float b2v = b2[0];

    for (int j0 = 0; j0 < N_; j0 += JT) {
        // Build P[jj][d] = s_i[d] * s_j0+jj[d]
        for (int e = t; e < JT * D_; e += 256) {
            int jj = e >> 7;            // D_==128
            int d  = e & (D_ - 1);
            P[jj * (D_ + 1) + d] = sish[d] * Sb[(size_t)(j0 + jj) * D_ + d];
        }
        __syncthreads();

        int j = j0 + lane;
        const float* bjP = bvec + ((size_t)b * N_ + j) * H_ + g * 64;

        float acc[64];
        #pragma unroll
        for (int kk = 0; kk < 64; ++kk) acc[kk] = aiP[kk] + bjP[kk];

        const float* Prow = &P[lane * (D_ + 1)];
        for (int d = 0; d < D_; ++d) {
            float p = Prow[d];
            const float* wrow = Wc + (size_t)d * H_;
            #pragma unroll
            for (int kk = 0; kk < 64; ++kk)
                acc[kk] = fmaf(p, wrow[kk], acc[kk]);
        }

        float sc = 0.f;
        #pragma unroll
        for (int kk = 0; kk < 64; ++kk)
            sc += fmaxf(acc[kk], 0.f) * w2P[kk];

        partial[wid][lane] = sc;
        __syncthreads();
        if (wid == 0) {
            float tot = partial[0][lane] + partial[1][lane]
                      + partial[2][lane] + partial[3][lane] + b2v;
            scores[(size_t)bi * N_ + j] = tot;
        }
        __syncthreads();
    }
}

// Kernel B: top-8 per row (smaller-index tiebreak, matching lax.top_k set),
// then gate / w / ctx.
__global__ __launch_bounds__(256) void topk_kernel(
    const float* __restrict__ s, const float* __restrict__ scores,
    float* __restrict__ ctx, float* __restrict__ gate, float* __restrict__ w)
{
    int bi = blockIdx.x;
    int b = bi >> 8;
    int t = threadIdx.x;

    __shared__ float v[N_];
    __shared__ int   ix[N_];
    __shared__ int   sel[N_];
    __shared__ int   chosen[K_];

    float sc = scores[(size_t)bi * N_ + t];
    sel[t] = 0;
    __syncthreads();

    for (int it = 0; it < K_; ++it) {
        v[t]  = sel[t] ? -INFINITY : sc;
        ix[t] = t;
        __syncthreads();
        for (int stp = N_ / 2; stp > 0; stp >>= 1) {
            if (t < stp) {
                float v2 = v[t + stp]; int i2 = ix[t + stp];
                if (v2 > v[t] || (v2 == v[t] && i2 < ix[t])) {
                    v[t] = v2; ix[t] = i2;
                }
            }
            __syncthreads();
        }
        if (t == 0) { chosen[it] = ix[0]; sel[ix[0]] = 1; }
        __syncthreads();
    }

    float gv = sel[t] ? 1.f : 0.f;
    gate[(size_t)bi * N_ + t] = gv;
    w[(size_t)bi * N_ + t]    = gv * (1.f / K_);

    if (t < D_) {
        float acc = 0.f;
        #pragma unroll
        for (int m = 0; m < K_; ++m)
            acc += s[((size_t)b * N_ + chosen[m]) * D_ + t];
        ctx[(size_t)bi * D_ + t] = acc * (1.f / K_);
    }
}

extern "C" void kernel_launch(void* const* d_in, const int* in_sizes, int n_in,
                              void* d_out, int out_size, void* d_ws, size_t ws_size,
                              hipStream_t stream)
{
    const float* s  = (const float*)d_in[0];
    const float* W1 = (const float*)d_in[1];
    const float* b1 = (const float*)d_in[2];
    const float* W2 = (const float*)d_in[3];
    const float* b2 = (const float*)d_in[4];
    // d_in[5] is K (==8), baked in as K_.

    float* avec   = (float*)d_ws;                       // B*N*H
    float* bvec   = avec + (size_t)B_ * N_ * H_;        // B*N*H
    float* scores = bvec + (size_t)B_ * N_ * H_;        // B*N*N

    float* ctx  = (float*)d_out;                        // B*N*D
    float* gate = ctx + (size_t)B_ * N_ * D_;           // B*N*N
    float* wout = gate + (size_t)B_ * N_ * N_;          // B*N*N

    precompute_ab<<<B_ * N_, 256, 0, stream>>>(s, W1, b1, avec, bvec);
    scores_kernel<<<B_ * N_, 256, 0, stream>>>(s, W1, W2, b2, avec, bvec, scores);
    topk_kernel  <<<B_ * N_, 256, 0, stream>>>(s, scores, ctx, gate, wout);
}

// Round 3
// 203.935 us; speedup vs baseline: 1.4570x; 1.4570x over previous
//
#include <hip/hip_runtime.h>
#include <hip/hip_bf16.h>
#include <math.h>

#define B_ 4
#define N_ 256
#define D_ 128
#define H_ 256
#define K_ 8

typedef __attribute__((ext_vector_type(8))) short short8;
typedef __attribute__((ext_vector_type(4))) float f32x4;

__device__ __forceinline__ unsigned short f2bf(float x) {
    union { __hip_bfloat16 h; unsigned short s; } u;
    u.h = __float2bfloat16(x);
    return u.s;
}
__device__ __forceinline__ float bf2f(unsigned short b) {
    unsigned v = ((unsigned)b) << 16;
    return __builtin_bit_cast(float, v);
}

// K0a: avec[bi][k] = b1[k] + sum_d s_i[d]*W1[d][k] ; bvec[bi][k] = sum_d s_i[d]*W1[D+d][k]
__global__ __launch_bounds__(256) void precompute_ab(
    const float* __restrict__ s, const float* __restrict__ W1,
    const float* __restrict__ b1,
    float* __restrict__ avec, float* __restrict__ bvec)
{
    int bi = blockIdx.x;
    int t = threadIdx.x;
    __shared__ float si[D_];
    if (t < D_) si[t] = s[(size_t)bi * D_ + t];
    __syncthreads();
    float a = b1[t], bb = 0.f;
    #pragma unroll 8
    for (int d = 0; d < D_; ++d) {
        float sv = si[d];
        a  = fmaf(sv, W1[(size_t)d * H_ + t], a);
        bb = fmaf(sv, W1[(size_t)(D_ + d) * H_ + t], bb);
    }
    avec[(size_t)bi * H_ + t] = a;
    bvec[(size_t)bi * H_ + t] = bb;
}

// K0b: Wt[h][d] = bf16(W1c[d][h])  (transposed, d-contiguous rows for B-frag b128 reads)
__global__ __launch_bounds__(256) void convert_w(
    const float* __restrict__ W1, unsigned short* __restrict__ Wt)
{
    int e = blockIdx.x * 256 + threadIdx.x;   // 32768 elements
    int h = e >> 7, d = e & 127;
    Wt[e] = f2bf(W1[(size_t)(2 * D_ + d) * H_ + h]);
}

// K1: approximate scores via bf16 MFMA.
// Block = (b,i,jtile of 64 j). 4 waves; chunk loop over h in 2 halves of 128;
// wave g owns 32 h within chunk (2 n-tiles). z-init carries exact fp32 a_i[h]+b_j[h].
#define PADB 136   // 128+8 bf16 elements per LDS row
__global__ __launch_bounds__(256) void approx_scores(
    const float* __restrict__ s, const unsigned short* __restrict__ Wt,
    const float* __restrict__ W2, const float* __restrict__ b2,
    const float* __restrict__ avec, const float* __restrict__ bvec,
    unsigned short* __restrict__ ascu)
{
    int bi = blockIdx.x >> 2;          // (b,i)
    int jt = blockIdx.x & 3;
    int j0 = jt * 64;
    int b  = bi >> 8;
    int t = threadIdx.x;
    int lane = t & 63;
    int g = __builtin_amdgcn_readfirstlane(t >> 6);
    int l15 = lane & 15, quad = lane >> 4;

    __shared__ __align__(16) short Wl[128 * PADB];  // 34816 B (one 128-h chunk)
    __shared__ __align__(16) short Pl[64 * PADB];   // 17408 B
    __shared__ float a_l[H_];
    __shared__ float w2_l[H_];
    __shared__ float spart[4][64];

    float b2v = b2[0];
    a_l[t]  = avec[(size_t)bi * H_ + t];
    w2_l[t] = W2[t];

    // Pl[jj][d] = bf16(s_i[d] * s_{j0+jj}[d])
    for (int c = t; c < 1024; c += 256) {
        int jj = c >> 4, dc = c & 15;
        const float4* sj = (const float4*)(s + ((size_t)(b * N_ + j0 + jj)) * D_ + dc * 8);
        const float4* si = (const float4*)(s + (size_t)bi * D_ + dc * 8);
        float4 A0 = sj[0], A1 = sj[1], S0 = si[0], S1 = si[1];
        short8 v;
        v[0] = (short)f2bf(A0.x * S0.x); v[1] = (short)f2bf(A0.y * S0.y);
        v[2] = (short)f2bf(A0.z * S0.z); v[3] = (short)f2bf(A0.w * S0.w);
        v[4] = (short)f2bf(A1.x * S1.x); v[5] = (short)f2bf(A1.y * S1.y);
        v[6] = (short)f2bf(A1.z * S1.z); v[7] = (short)f2bf(A1.w * S1.w);
        *(short8*)&Pl[jj * PADB + dc * 8] = v;
    }
    // stage W chunk 0
    for (int c = t; c < 2048; c += 256) {
        int rl = c >> 4, dc = c & 15;
        uint4 v = *(const uint4*)(Wt + (size_t)rl * D_ + dc * 8);
        *(uint4*)&Wl[rl * PADB + dc * 8] = v;
    }
    __syncthreads();

    for (int hc = 0; hc < 2; ++hc) {
        if (hc == 1) {
            __syncthreads();
            for (int c = t; c < 2048; c += 256) {
                int rl = c >> 4, dc = c & 15;
                uint4 v = *(const uint4*)(Wt + (size_t)(128 + rl) * D_ + dc * 8);
                *(uint4*)&Wl[rl * PADB + dc * 8] = v;
            }
            __syncthreads();
        }

        f32x4 acc[4][2];
        // init with exact fp32 a_i[h] + b_j[h]
        #pragma unroll
        for (int mi = 0; mi < 4; ++mi) {
            #pragma unroll
            for (int r = 0; r < 4; ++r) {
                int j = j0 + mi * 16 + quad * 4 + r;
                const float* bv = bvec + ((size_t)(b * N_ + j)) * H_ + hc * 128 + g * 32 + l15;
                #pragma unroll
                for (int ni = 0; ni < 2; ++ni)
                    acc[mi][ni][r] = bv[ni * 16] + a_l[hc * 128 + g * 32 + ni * 16 + l15];
            }
        }
        // GEMM over d
        #pragma unroll
        for (int dk = 0; dk < 128; dk += 32) {
            short8 af[4], bfr[2];
            #pragma unroll
            for (int mi = 0; mi < 4; ++mi)
                af[mi] = *(const short8*)&Pl[(mi * 16 + l15) * PADB + dk + quad * 8];
            #pragma unroll
            for (int ni = 0; ni < 2; ++ni)
                bfr[ni] = *(const short8*)&Wl[(g * 32 + ni * 16 + l15) * PADB + dk + quad * 8];
            #pragma unroll
            for (int mi = 0; mi < 4; ++mi)
                #pragma unroll
                for (int ni = 0; ni < 2; ++ni)
                    acc[mi][ni] = __builtin_amdgcn_mfma_f32_16x16x32_bf16(
                        af[mi], bfr[ni], acc[mi][ni], 0, 0, 0);
        }
        // epilogue: relu * W2, reduce over h
        #pragma unroll
        for (int mi = 0; mi < 4; ++mi) {
            float rs[4];
            #pragma unroll
            for (int r = 0; r < 4; ++r) {
                float v = 0.f;
                #pragma unroll
                for (int ni = 0; ni < 2; ++ni)
                    v += fmaxf(acc[mi][ni][r], 0.f) * w2_l[hc * 128 + g * 32 + ni * 16 + l15];
                rs[r] = v;
            }
            #pragma unroll
            for (int mask = 1; mask < 16; mask <<= 1)
                #pragma unroll
                for (int r = 0; r < 4; ++r)
                    rs[r] += __shfl_xor(rs[r], mask);
            if (l15 == 0) {
                #pragma unroll
                for (int r = 0; r < 4; ++r) {
                    int jl = mi * 16 + quad * 4 + r;
                    if (hc == 0) spart[g][jl] = rs[r];
                    else         spart[g][jl] += rs[r];
                }
            }
        }
    }
    __syncthreads();
    if (t < 64) {
        float v = spart[0][t] + spart[1][t] + spart[2][t] + spart[3][t] + b2v;
        ascu[(size_t)bi * N_ + j0 + t] = f2bf(v);
    }
}

// K2: per block = 4 rows. Select approx-top-16, rescore exactly in fp32,
// top-8 among 16 (value desc, index asc), write gate/w/ctx.
#define PADP 129
__global__ __launch_bounds__(256) void finalize_kernel(
    const float* __restrict__ s, const float* __restrict__ W1,
    const float* __restrict__ W2, const float* __restrict__ b2,
    const float* __restrict__ avec, const float* __restrict__ bvec,
    const unsigned short* __restrict__ ascu,
    float* __restrict__ ctx, float* __restrict__ gate, float* __restrict__ w)
{
    int bi0 = blockIdx.x * 4;          // grid must be B_*N_/4 blocks!
    int b = bi0 >> 8;
    int t = threadIdx.x;
    int lane = t & 63;
    int g = __builtin_amdgcn_readfirstlane(t >> 6);

    __shared__ float asc[4][N_];
    __shared__ int cand[4][16];
    __shared__ __align__(16) float Pl2[64 * PADP];
    __shared__ float spart2[4][64];
    __shared__ float rsc[4][16];
    __shared__ int sel8[4][8];

    // load approx scores
    for (int e = t; e < 4 * N_; e += 256) {
        int r = e >> 8, j = e & 255;
        asc[r][j] = bf2f(ascu[(size_t)(bi0 + r) * N_ + j]);
    }
    __syncthreads();

    // rank-select top-16 per row; wave g owns row g
    {
        int r = g;
        for (int m = 0; m < 4; ++m) {
            int jj = m * 64 + lane;
            float my = asc[r][jj];
            int rank = 0;
            #pragma unroll 8
            for (int j2 = 0; j2 < N_; ++j2) {
                float o = asc[r][j2];
                rank += (o > my) || (o == my && j2 < jj);
            }
            if (rank < 16) cand[r][rank] = jj;
        }
    }
    __syncthreads();

    // build P rows for the 64 (row, cand) pairs
    for (int e = t; e < 2048; e += 256) {
        int p = e >> 5, dc = e & 31;
        int r = p >> 4, c = p & 15;
        int j = cand[r][c];
        float4 sj = *(const float4*)(s + ((size_t)(b * N_ + j)) * D_ + dc * 4);
        float4 si = *(const float4*)(s + ((size_t)(bi0 + r)) * D_ + dc * 4);
        int base = p * PADP + dc * 4;
        Pl2[base + 0] = si.x * sj.x;
        Pl2[base + 1] = si.y * sj.y;
        Pl2[base + 2] = si.z * sj.z;
        Pl2[base + 3] = si.w * sj.w;
    }
    __syncthreads();

    // exact fp32 rescore: lane = pair, wave g = k-slice [64g,64g+64)
    {
        int r = lane >> 4, c = lane & 15;
        int j = cand[r][c];
        const float* Wc = W1 + (size_t)2 * D_ * H_ + g * 64;
        const float* av = avec + (size_t)(bi0 + r) * H_ + g * 64;
        const float* bv = bvec + ((size_t)(b * N_ + j)) * H_ + g * 64;
        float acc[64];
        #pragma unroll
        for (int kk = 0; kk < 64; ++kk) acc[kk] = av[kk] + bv[kk];
        const float* Prow = &Pl2[lane * PADP];
        for (int d = 0; d < D_; ++d) {
            float p = Prow[d];
            const float* wrow = Wc + (size_t)d * H_;
            #pragma unroll
            for (int kk = 0; kk < 64; ++kk)
                acc[kk] = fmaf(p, wrow[kk], acc[kk]);
        }
        const float* w2P = W2 + g * 64;
        float sc = 0.f;
        #pragma unroll
        for (int kk = 0; kk < 64; ++kk)
            sc += fmaxf(acc[kk], 0.f) * w2P[kk];
        spart2[g][lane] = sc;
    }
    __syncthreads();
    if (t < 64) {
        int r = t >> 4, c = t & 15;
        rsc[r][c] = spart2[0][t] + spart2[1][t] + spart2[2][t] + spart2[3][t] + b2[0];
    }
    __syncthreads();

    // top-8 among 16 exact scores, tiebreak smaller original index
    if (t < 64) {
        int r = t >> 4, c = t & 15;
        float my = rsc[r][c]; int myj = cand[r][c];
        int rank = 0;
        #pragma unroll
        for (int c2 = 0; c2 < 16; ++c2) {
            float o = rsc[r][c2]; int oj = cand[r][c2];
            rank += (o > my) || (o == my && oj < myj);
        }
        if (rank < 8) sel8[r][rank] = myj;
    }
    __syncthreads();

    // gate / w
    for (int e = t; e < 4 * N_; e += 256) {
        int r = e >> 8, jj = e & 255;
        float gv = 0.f;
        #pragma unroll
        for (int m = 0; m < 8; ++m)
            gv = (jj == sel8[r][m]) ? 1.f : gv;
        gate[(size_t)(bi0 + r) * N_ + jj] = gv;
        w[(size_t)(bi0 + r) * N_ + jj]    = gv * 0.125f;
    }
    // ctx
    for (int e = t; e < 4 * D_; e += 256) {
        int r = e >> 7, d = e & 127;
        float a = 0.f;
        #pragma unroll
        for (int m = 0; m < 8; ++m)
            a += s[((size_t)(b * N_ + sel8[r][m])) * D_ + d];
        ctx[(size_t)(bi0 + r) * D_ + d] = a * 0.125f;
    }
}

extern "C" void kernel_launch(void* const* d_in, const int* in_sizes, int n_in,
                              void* d_out, int out_size, void* d_ws, size_t ws_size,
                              hipStream_t stream)
{
    const float* s  = (const float*)d_in[0];
    const float* W1 = (const float*)d_in[1];
    const float* b1 = (const float*)d_in[2];
    const float* W2 = (const float*)d_in[3];
    const float* b2 = (const float*)d_in[4];

    float* avec = (float*)d_ws;                                    // 262144 f
    float* bvec = avec + (size_t)B_ * N_ * H_;                     // 262144 f
    unsigned short* ascu = (unsigned short*)(bvec + (size_t)B_ * N_ * H_); // 262144 us
    unsigned short* Wtu  = ascu + (size_t)B_ * N_ * N_;            // 32768 us

    float* ctx  = (float*)d_out;
    float* gate = ctx + (size_t)B_ * N_ * D_;
    float* wout = gate + (size_t)B_ * N_ * N_;

    precompute_ab<<<B_ * N_, 256, 0, stream>>>(s, W1, b1, avec, bvec);
    convert_w<<<128, 256, 0, stream>>>(W1, Wtu);
    approx_scores<<<B_ * N_ * 4, 256, 0, stream>>>(s, Wtu, W2, b2, avec, bvec, ascu);
    // 4 rows per block -> B_*N_/4 = 256 blocks (1024 was the R1 OOB crash)
    finalize_kernel<<<B_ * N_ / 4, 256, 0, stream>>>(s, W1, W2, b2, avec, bvec, ascu,
                                                     ctx, gate, wout);
}

// Round 4
// 185.519 us; speedup vs baseline: 1.6016x; 1.0993x over previous
//
#include <hip/hip_runtime.h>
#include <hip/hip_bf16.h>
#include <math.h>

#define B_ 4
#define N_ 256
#define D_ 128
#define H_ 256
#define K_ 8

typedef __attribute__((ext_vector_type(8))) short short8;
typedef __attribute__((ext_vector_type(4))) float f32x4;

__device__ __forceinline__ unsigned short f2bf(float x) {
    union { __hip_bfloat16 h; unsigned short s; } u;
    u.h = __float2bfloat16(x);
    return u.s;
}
__device__ __forceinline__ short f2bfs(float x) { return (short)f2bf(x); }
__device__ __forceinline__ float bf2f(unsigned short b) {
    unsigned v = ((unsigned)b) << 16;
    return __builtin_bit_cast(float, v);
}

// K0 (fused): blocks 0..255: avec/bvec (4 i-rows per block, W1 cols hoisted);
//             blocks 256..383: Wt[h][d] = bf16(W1c[d][h]).
__global__ __launch_bounds__(256) void pre_kernel(
    const float* __restrict__ s, const float* __restrict__ W1,
    const float* __restrict__ b1,
    float* __restrict__ avec, float* __restrict__ bvec,
    unsigned short* __restrict__ Wt)
{
    int blk = blockIdx.x;
    int t = threadIdx.x;
    if (blk < 256) {
        int bi0 = blk * 4;
        __shared__ float s4[4][D_];
        for (int idx = t; idx < 4 * D_; idx += 256) {
            int r = idx >> 7, d = idx & 127;
            s4[r][d] = s[(size_t)(bi0 + r) * D_ + d];
        }
        __syncthreads();
        float aA[4], aB[4];
        float b1v = b1[t];
        #pragma unroll
        for (int r = 0; r < 4; ++r) { aA[r] = b1v; aB[r] = 0.f; }
        for (int d = 0; d < D_; ++d) {
            float wa = W1[(size_t)d * H_ + t];
            float wb = W1[(size_t)(D_ + d) * H_ + t];
            #pragma unroll
            for (int r = 0; r < 4; ++r) {
                aA[r] = fmaf(s4[r][d], wa, aA[r]);
                aB[r] = fmaf(s4[r][d], wb, aB[r]);
            }
        }
        #pragma unroll
        for (int r = 0; r < 4; ++r) {
            avec[(size_t)(bi0 + r) * H_ + t] = aA[r];
            bvec[(size_t)(bi0 + r) * H_ + t] = aB[r];
        }
    } else {
        int e = (blk - 256) * 256 + t;     // 32768 elements
        int h = e >> 7, d = e & 127;
        Wt[e] = f2bf(W1[(size_t)(2 * D_ + d) * H_ + h]);
    }
}

// K1: approx scores. Block = (b,i), 512 thr = 8 waves = (jg 0..3) x (hg 0..1).
// P (256j x 128d bf16, XOR-swizzled, exactly 64 KB LDS); W frags held in VGPRs
// from global; z = P@Wc (MFMA) + a_i[h] + b_j[h] (epilogue); relu*W2 reduce.
__global__ __launch_bounds__(512, 2) void approx_scores(
    const float* __restrict__ s, const unsigned short* __restrict__ Wt,
    const float* __restrict__ W2, const float* __restrict__ b2,
    const float* __restrict__ avec, const float* __restrict__ bvec,
    unsigned short* __restrict__ ascu)
{
    int bi = blockIdx.x;
    int b  = bi >> 8;
    int t = threadIdx.x;
    int lane = t & 63;
    int wid = __builtin_amdgcn_readfirstlane(t >> 6);
    int jg = wid & 3, hg = wid >> 2;
    int l15 = lane & 15, quad = lane >> 4;

    __shared__ __align__(16) unsigned char lds_raw[65536];
    short* Pl = (short*)lds_raw;          // during GEMM: P tiles
    float* Pf = (float*)lds_raw;          // after barrier: per-wave partials

    // ---- build P: Pl[row][d], chunk-swizzled: phys16B = log16B ^ (row & 15)
    {
        int d0 = (t & 15) * 8;
        const float* siP = s + (size_t)bi * D_ + d0;
        float4 si0 = *(const float4*)siP;
        float4 si1 = *(const float4*)(siP + 4);
        int rbase = t >> 4;                         // 0..31
        int pc = (t & 15) ^ (rbase & 15);
        #pragma unroll
        for (int k = 0; k < 8; ++k) {
            int row = rbase + 32 * k;
            const float* sjP = s + ((size_t)(b * N_ + row)) * D_ + d0;
            float4 a0 = *(const float4*)sjP;
            float4 a1 = *(const float4*)(sjP + 4);
            short8 v;
            v[0] = f2bfs(a0.x * si0.x); v[1] = f2bfs(a0.y * si0.y);
            v[2] = f2bfs(a0.z * si0.z); v[3] = f2bfs(a0.w * si0.w);
            v[4] = f2bfs(a1.x * si1.x); v[5] = f2bfs(a1.y * si1.y);
            v[6] = f2bfs(a1.z * si1.z); v[7] = f2bfs(a1.w * si1.w);
            *(short8*)&Pl[row * 128 + pc * 8] = v;
        }
    }
    // per-lane h-constants for this wave's 128-h slice
    float av[8], w2v[8];
    #pragma unroll
    for (int ni = 0; ni < 8; ++ni) {
        int h = hg * 128 + ni * 16 + l15;
        av[ni]  = avec[(size_t)bi * H_ + h];
        w2v[ni] = W2[h];
    }
    __syncthreads();

    float rsAll[4][4];                    // [mi][r] partial scores
    #pragma unroll
    for (int mi = 0; mi < 4; ++mi)
        #pragma unroll
        for (int r = 0; r < 4; ++r) rsAll[mi][r] = 0.f;

    for (int half = 0; half < 2; ++half) {
        // hold this half's W fragments (64 h x 128 d) in regs, straight from global
        short8 Bf[4][4];                  // [nni][dk]
        #pragma unroll
        for (int nni = 0; nni < 4; ++nni) {
            int h = hg * 128 + half * 64 + nni * 16 + l15;
            #pragma unroll
            for (int dk = 0; dk < 4; ++dk)
                Bf[nni][dk] = *(const short8*)(Wt + (size_t)h * D_ + dk * 32 + quad * 8);
        }
        #pragma unroll 1
        for (int mi = 0; mi < 4; ++mi) {
            int jb = jg * 64 + mi * 16;
            // A frags from swizzled LDS
            short8 Af[4];
            #pragma unroll
            for (int dk = 0; dk < 4; ++dk) {
                int pcc = (4 * dk + quad) ^ l15;
                Af[dk] = *(const short8*)&Pl[(jb + l15) * 128 + pcc * 8];
            }
            // b_j[h] loads: issued now, consumed after the MFMAs (latency hidden)
            float bv[4][4];
            #pragma unroll
            for (int nni = 0; nni < 4; ++nni) {
                int h = hg * 128 + half * 64 + nni * 16 + l15;
                #pragma unroll
                for (int r = 0; r < 4; ++r)
                    bv[nni][r] = bvec[((size_t)(b * N_ + jb + quad * 4 + r)) * H_ + h];
            }
            f32x4 acc[4];
            #pragma unroll
            for (int nni = 0; nni < 4; ++nni)
                acc[nni] = (f32x4){0.f, 0.f, 0.f, 0.f};
            #pragma unroll
            for (int dk = 0; dk < 4; ++dk)
                #pragma unroll
                for (int nni = 0; nni < 4; ++nni)
                    acc[nni] = __builtin_amdgcn_mfma_f32_16x16x32_bf16(
                        Af[dk], Bf[nni][dk], acc[nni], 0, 0, 0);
            // fold: z = bilinear + a + b ; rs += relu(z)*w2
            #pragma unroll
            for (int r = 0; r < 4; ++r) {
                float rs = rsAll[mi][r];
                #pragma unroll
                for (int nni = 0; nni < 4; ++nni) {
                    int ni = half * 4 + nni;
                    float z = acc[nni][r] + av[ni] + bv[nni][r];
                    rs = fmaf(fmaxf(z, 0.f), w2v[ni], rs);
                }
                rsAll[mi][r] = rs;
            }
        }
    }
    __syncthreads();                      // all A-reads done; Pl is dead
    #pragma unroll
    for (int mi = 0; mi < 4; ++mi)
        #pragma unroll
        for (int r = 0; r < 4; ++r) {
            float v = rsAll[mi][r];
            v += __shfl_xor(v, 1); v += __shfl_xor(v, 2);
            v += __shfl_xor(v, 4); v += __shfl_xor(v, 8);
            if (l15 == 0)
                Pf[hg * 256 + jg * 64 + mi * 16 + quad * 4 + r] = v;
        }
    __syncthreads();
    if (t < 256) {
        float v = Pf[t] + Pf[256 + t] + b2[0];
        ascu[(size_t)bi * N_ + t] = f2bf(v);
    }
}

// K2: per block = 4 rows. Approx-top-16, exact fp32 rescore, top-8 of 16,
// write gate/w/ctx.  (Unchanged from R3 — passed.)
#define PADP 129
__global__ __launch_bounds__(256) void finalize_kernel(
    const float* __restrict__ s, const float* __restrict__ W1,
    const float* __restrict__ W2, const float* __restrict__ b2,
    const float* __restrict__ avec, const float* __restrict__ bvec,
    const unsigned short* __restrict__ ascu,
    float* __restrict__ ctx, float* __restrict__ gate, float* __restrict__ w)
{
    int bi0 = blockIdx.x * 4;
    int b = bi0 >> 8;
    int t = threadIdx.x;
    int lane = t & 63;
    int g = __builtin_amdgcn_readfirstlane(t >> 6);

    __shared__ float asc[4][N_];
    __shared__ int cand[4][16];
    __shared__ __align__(16) float Pl2[64 * PADP];
    __shared__ float spart2[4][64];
    __shared__ float rsc[4][16];
    __shared__ int sel8[4][8];

    for (int e = t; e < 4 * N_; e += 256) {
        int r = e >> 8, j = e & 255;
        asc[r][j] = bf2f(ascu[(size_t)(bi0 + r) * N_ + j]);
    }
    __syncthreads();

    {
        int r = g;
        for (int m = 0; m < 4; ++m) {
            int jj = m * 64 + lane;
            float my = asc[r][jj];
            int rank = 0;
            #pragma unroll 8
            for (int j2 = 0; j2 < N_; ++j2) {
                float o = asc[r][j2];
                rank += (o > my) || (o == my && j2 < jj);
            }
            if (rank < 16) cand[r][rank] = jj;
        }
    }
    __syncthreads();

    for (int e = t; e < 2048; e += 256) {
        int p = e >> 5, dc = e & 31;
        int r = p >> 4, c = p & 15;
        int j = cand[r][c];
        float4 sj = *(const float4*)(s + ((size_t)(b * N_ + j)) * D_ + dc * 4);
        float4 si = *(const float4*)(s + ((size_t)(bi0 + r)) * D_ + dc * 4);
        int base = p * PADP + dc * 4;
        Pl2[base + 0] = si.x * sj.x;
        Pl2[base + 1] = si.y * sj.y;
        Pl2[base + 2] = si.z * sj.z;
        Pl2[base + 3] = si.w * sj.w;
    }
    __syncthreads();

    {
        int r = lane >> 4, c = lane & 15;
        int j = cand[r][c];
        const float* Wc = W1 + (size_t)2 * D_ * H_ + g * 64;
        const float* av = avec + (size_t)(bi0 + r) * H_ + g * 64;
        const float* bvp = bvec + ((size_t)(b * N_ + j)) * H_ + g * 64;
        float acc[64];
        #pragma unroll
        for (int kk = 0; kk < 64; ++kk) acc[kk] = av[kk] + bvp[kk];
        const float* Prow = &Pl2[lane * PADP];
        for (int d = 0; d < D_; ++d) {
            float p = Prow[d];
            const float* wrow = Wc + (size_t)d * H_;
            #pragma unroll
            for (int kk = 0; kk < 64; ++kk)
                acc[kk] = fmaf(p, wrow[kk], acc[kk]);
        }
        const float* w2P = W2 + g * 64;
        float sc = 0.f;
        #pragma unroll
        for (int kk = 0; kk < 64; ++kk)
            sc += fmaxf(acc[kk], 0.f) * w2P[kk];
        spart2[g][lane] = sc;
    }
    __syncthreads();
    if (t < 64) {
        int r = t >> 4, c = t & 15;
        rsc[r][c] = spart2[0][t] + spart2[1][t] + spart2[2][t] + spart2[3][t] + b2[0];
    }
    __syncthreads();

    if (t < 64) {
        int r = t >> 4, c = t & 15;
        float my = rsc[r][c]; int myj = cand[r][c];
        int rank = 0;
        #pragma unroll
        for (int c2 = 0; c2 < 16; ++c2) {
            float o = rsc[r][c2]; int oj = cand[r][c2];
            rank += (o > my) || (o == my && oj < myj);
        }
        if (rank < 8) sel8[r][rank] = myj;
    }
    __syncthreads();

    for (int e = t; e < 4 * N_; e += 256) {
        int r = e >> 8, jj = e & 255;
        float gv = 0.f;
        #pragma unroll
        for (int m = 0; m < 8; ++m)
            gv = (jj == sel8[r][m]) ? 1.f : gv;
        gate[(size_t)(bi0 + r) * N_ + jj] = gv;
        w[(size_t)(bi0 + r) * N_ + jj]    = gv * 0.125f;
    }
    for (int e = t; e < 4 * D_; e += 256) {
        int r = e >> 7, d = e & 127;
        float a = 0.f;
        #pragma unroll
        for (int m = 0; m < 8; ++m)
            a += s[((size_t)(b * N_ + sel8[r][m])) * D_ + d];
        ctx[(size_t)(bi0 + r) * D_ + d] = a * 0.125f;
    }
}

extern "C" void kernel_launch(void* const* d_in, const int* in_sizes, int n_in,
                              void* d_out, int out_size, void* d_ws, size_t ws_size,
                              hipStream_t stream)
{
    const float* s  = (const float*)d_in[0];
    const float* W1 = (const float*)d_in[1];
    const float* b1 = (const float*)d_in[2];
    const float* W2 = (const float*)d_in[3];
    const float* b2 = (const float*)d_in[4];

    float* avec = (float*)d_ws;                                           // 262144 f
    float* bvec = avec + (size_t)B_ * N_ * H_;                            // 262144 f
    unsigned short* ascu = (unsigned short*)(bvec + (size_t)B_ * N_ * H_);// 262144 us
    unsigned short* Wtu  = ascu + (size_t)B_ * N_ * N_;                   // 32768 us

    float* ctx  = (float*)d_out;
    float* gate = ctx + (size_t)B_ * N_ * D_;
    float* wout = gate + (size_t)B_ * N_ * N_;

    pre_kernel<<<384, 256, 0, stream>>>(s, W1, b1, avec, bvec, Wtu);
    approx_scores<<<B_ * N_, 512, 0, stream>>>(s, Wtu, W2, b2, avec, bvec, ascu);
    finalize_kernel<<<B_ * N_ / 4, 256, 0, stream>>>(s, W1, W2, b2, avec, bvec, ascu,
                                                     ctx, gate, wout);
}